// Round 1
// baseline (848.108 us; speedup 1.0000x reference)
//
#include <hip/hip_runtime.h>
#include <math.h>

// StructuralSparseBlock: gather -> (Dense 128x128 + exact GELU) x2 -> +residual -> LayerNorm
// B=16384, E=2048, G=32, D=128, L=2, fp32 in/out.

constexpr int E_DIM = 2048;
constexpr int G_DIM = 32;
constexpr int D_DIM = 128;
constexpr int L_DIM = 2;
constexpr float LN_EPS = 1e-3f;

constexpr int BM   = 64;          // rows per block
constexpr int LDSW = D_DIM + 4;   // 132 floats: rows 4 apart differ by 16 banks -> 2-way (free); keeps 16B align

__device__ __forceinline__ float gelu_exact(float v) {
    return 0.5f * v * (1.0f + erff(v * 0.70710678118654752f));
}

__global__ __launch_bounds__(256) void ssb_fp32_kernel(
    const float* __restrict__ x,
    const int*   __restrict__ idx,
    const float* __restrict__ W,
    const float* __restrict__ bias,
    const float* __restrict__ gamma,
    const float* __restrict__ beta,
    float* __restrict__ out)
{
    __shared__ float sBuf[BM * LDSW];   // gather tile, then layer-0 activation tile
    __shared__ int   sIdx[D_DIM];

    const int g    = blockIdx.y;
    const int row0 = blockIdx.x * BM;
    const int tid  = threadIdx.x;
    const int tx   = tid & 15;   // column group: cols 8*tx .. 8*tx+7
    const int ty   = tid >> 4;   // row group:   rows 4*ty .. 4*ty+3

    if (tid < D_DIM) sIdx[tid] = idx[g * D_DIM + tid];
    __syncthreads();

    // ---------- gather: x[row, idx[g][d]] -> sBuf, residual kept in registers ----------
    float gres[4][8];
    #pragma unroll
    for (int i = 0; i < 4; ++i) {
        const int r = 4 * ty + i;
        const float* xr = x + (size_t)(row0 + r) * E_DIM;
        #pragma unroll
        for (int c = 0; c < 8; ++c) gres[i][c] = xr[sIdx[8 * tx + c]];
        float4* dst = (float4*)(sBuf + r * LDSW + 8 * tx);
        dst[0] = make_float4(gres[i][0], gres[i][1], gres[i][2], gres[i][3]);
        dst[1] = make_float4(gres[i][4], gres[i][5], gres[i][6], gres[i][7]);
    }
    __syncthreads();

    float acc[4][8];

    // ================= layer 0: sBuf -> gelu -> sBuf =================
    {
        const float* Wl = W + (size_t)(g * L_DIM + 0) * D_DIM * D_DIM;
        const float* bl = bias + (g * L_DIM + 0) * D_DIM;
        const float4 b0 = *(const float4*)(bl + 8 * tx);
        const float4 b1 = *(const float4*)(bl + 8 * tx + 4);
        #pragma unroll
        for (int i = 0; i < 4; ++i) {
            acc[i][0] = b0.x; acc[i][1] = b0.y; acc[i][2] = b0.z; acc[i][3] = b0.w;
            acc[i][4] = b1.x; acc[i][5] = b1.y; acc[i][6] = b1.z; acc[i][7] = b1.w;
        }
        for (int k4 = 0; k4 < D_DIM; k4 += 4) {
            float4 hv[4];
            #pragma unroll
            for (int i = 0; i < 4; ++i)
                hv[i] = *(const float4*)(sBuf + (4 * ty + i) * LDSW + k4);
            #pragma unroll
            for (int kk = 0; kk < 4; ++kk) {
                const float* wrow = Wl + (size_t)(k4 + kk) * D_DIM + 8 * tx;
                const float4 wa = *(const float4*)(wrow);
                const float4 wb = *(const float4*)(wrow + 4);
                #pragma unroll
                for (int i = 0; i < 4; ++i) {
                    const float h = (&hv[i].x)[kk];
                    acc[i][0] = fmaf(h, wa.x, acc[i][0]);
                    acc[i][1] = fmaf(h, wa.y, acc[i][1]);
                    acc[i][2] = fmaf(h, wa.z, acc[i][2]);
                    acc[i][3] = fmaf(h, wa.w, acc[i][3]);
                    acc[i][4] = fmaf(h, wb.x, acc[i][4]);
                    acc[i][5] = fmaf(h, wb.y, acc[i][5]);
                    acc[i][6] = fmaf(h, wb.z, acc[i][6]);
                    acc[i][7] = fmaf(h, wb.w, acc[i][7]);
                }
            }
        }
        __syncthreads();   // everyone done READING sBuf before we overwrite it
        #pragma unroll
        for (int i = 0; i < 4; ++i) {
            const int r = 4 * ty + i;
            float4* dst = (float4*)(sBuf + r * LDSW + 8 * tx);
            dst[0] = make_float4(gelu_exact(acc[i][0]), gelu_exact(acc[i][1]),
                                 gelu_exact(acc[i][2]), gelu_exact(acc[i][3]));
            dst[1] = make_float4(gelu_exact(acc[i][4]), gelu_exact(acc[i][5]),
                                 gelu_exact(acc[i][6]), gelu_exact(acc[i][7]));
        }
    }
    __syncthreads();

    // ================= layer 1: sBuf -> registers, then epilogue =================
    {
        const float* Wl = W + (size_t)(g * L_DIM + 1) * D_DIM * D_DIM;
        const float* bl = bias + (g * L_DIM + 1) * D_DIM;
        const float4 b0 = *(const float4*)(bl + 8 * tx);
        const float4 b1 = *(const float4*)(bl + 8 * tx + 4);
        #pragma unroll
        for (int i = 0; i < 4; ++i) {
            acc[i][0] = b0.x; acc[i][1] = b0.y; acc[i][2] = b0.z; acc[i][3] = b0.w;
            acc[i][4] = b1.x; acc[i][5] = b1.y; acc[i][6] = b1.z; acc[i][7] = b1.w;
        }
        for (int k4 = 0; k4 < D_DIM; k4 += 4) {
            float4 hv[4];
            #pragma unroll
            for (int i = 0; i < 4; ++i)
                hv[i] = *(const float4*)(sBuf + (4 * ty + i) * LDSW + k4);
            #pragma unroll
            for (int kk = 0; kk < 4; ++kk) {
                const float* wrow = Wl + (size_t)(k4 + kk) * D_DIM + 8 * tx;
                const float4 wa = *(const float4*)(wrow);
                const float4 wb = *(const float4*)(wrow + 4);
                #pragma unroll
                for (int i = 0; i < 4; ++i) {
                    const float h = (&hv[i].x)[kk];
                    acc[i][0] = fmaf(h, wa.x, acc[i][0]);
                    acc[i][1] = fmaf(h, wa.y, acc[i][1]);
                    acc[i][2] = fmaf(h, wa.z, acc[i][2]);
                    acc[i][3] = fmaf(h, wa.w, acc[i][3]);
                    acc[i][4] = fmaf(h, wb.x, acc[i][4]);
                    acc[i][5] = fmaf(h, wb.y, acc[i][5]);
                    acc[i][6] = fmaf(h, wb.z, acc[i][6]);
                    acc[i][7] = fmaf(h, wb.w, acc[i][7]);
                }
            }
        }
        // gelu + residual + LayerNorm (all in registers; row reduce over the 16 tx lanes)
        const float4 gm0 = *(const float4*)(gamma + g * D_DIM + 8 * tx);
        const float4 gm1 = *(const float4*)(gamma + g * D_DIM + 8 * tx + 4);
        const float4 bt0 = *(const float4*)(beta  + g * D_DIM + 8 * tx);
        const float4 bt1 = *(const float4*)(beta  + g * D_DIM + 8 * tx + 4);
        #pragma unroll
        for (int i = 0; i < 4; ++i) {
            const int r = 4 * ty + i;
            float v[8];
            #pragma unroll
            for (int c = 0; c < 8; ++c) v[c] = gelu_exact(acc[i][c]) + gres[i][c];

            float s = 0.f;
            #pragma unroll
            for (int c = 0; c < 8; ++c) s += v[c];
            #pragma unroll
            for (int m = 8; m >= 1; m >>= 1) s += __shfl_xor(s, m, 64);
            const float mu = s * (1.0f / 128.0f);

            float q = 0.f;
            #pragma unroll
            for (int c = 0; c < 8; ++c) { const float d = v[c] - mu; q += d * d; }
            #pragma unroll
            for (int m = 8; m >= 1; m >>= 1) q += __shfl_xor(q, m, 64);
            const float rstd = rsqrtf(q * (1.0f / 128.0f) + LN_EPS);

            float o[8];
            o[0] = (v[0] - mu) * rstd * gm0.x + bt0.x;
            o[1] = (v[1] - mu) * rstd * gm0.y + bt0.y;
            o[2] = (v[2] - mu) * rstd * gm0.z + bt0.z;
            o[3] = (v[3] - mu) * rstd * gm0.w + bt0.w;
            o[4] = (v[4] - mu) * rstd * gm1.x + bt1.x;
            o[5] = (v[5] - mu) * rstd * gm1.y + bt1.y;
            o[6] = (v[6] - mu) * rstd * gm1.z + bt1.z;
            o[7] = (v[7] - mu) * rstd * gm1.w + bt1.w;

            float4* op = (float4*)(out + ((size_t)(row0 + r) * G_DIM + g) * D_DIM + 8 * tx);
            op[0] = make_float4(o[0], o[1], o[2], o[3]);
            op[1] = make_float4(o[4], o[5], o[6], o[7]);
        }
    }
}

extern "C" void kernel_launch(void* const* d_in, const int* in_sizes, int n_in,
                              void* d_out, int out_size, void* d_ws, size_t ws_size,
                              hipStream_t stream) {
    const float* x     = (const float*)d_in[0];
    const int*   idx   = (const int*)d_in[1];
    const float* W     = (const float*)d_in[2];
    const float* b     = (const float*)d_in[3];
    const float* gamma = (const float*)d_in[4];
    const float* beta  = (const float*)d_in[5];
    float* out = (float*)d_out;

    const int B = in_sizes[0] / E_DIM;   // 16384
    dim3 grid(B / BM, G_DIM);
    ssb_fp32_kernel<<<grid, 256, 0, stream>>>(x, idx, W, b, gamma, beta, out);
}

// Round 2
// 750.316 us; speedup vs baseline: 1.1303x; 1.1303x over previous
//
#include <hip/hip_runtime.h>
#include <math.h>

// StructuralSparseBlock: gather -> (Dense 128x128 + exact GELU) x2 -> +residual -> LayerNorm
// B=16384, E=2048, G=32, D=128, L=2, fp32 in/out.
// Two-pass: pass1 gathers x (each x row read from HBM once) into d_out's [B,G,D]
// layout; pass2 reads its own tile back, does the dense stack + LN, overwrites it.

constexpr int E_DIM = 2048;
constexpr int G_DIM = 32;
constexpr int D_DIM = 128;
constexpr int L_DIM = 2;
constexpr float LN_EPS = 1e-3f;

constexpr int ROWS1 = 4;          // rows per block, pass 1
constexpr int BM    = 64;         // rows per block, pass 2
constexpr int LDSW  = D_DIM + 4;  // 132 floats: rows 4 apart -> 2-way bank alias (free)

__device__ __forceinline__ float gelu_exact(float v) {
    return 0.5f * v * (1.0f + erff(v * 0.70710678118654752f));
}

// ---------------- pass 1: gather all groups, x rows staged in LDS ----------------
__global__ __launch_bounds__(256) void ssb_gather_kernel(
    const float* __restrict__ x,
    const int*   __restrict__ idx,
    float* __restrict__ out)
{
    __shared__ float sX[ROWS1][E_DIM];     // 32 KB
    __shared__ int   sIdx[G_DIM * D_DIM];  // 16 KB

    const int tid  = threadIdx.x;
    const int row0 = blockIdx.x * ROWS1;

    #pragma unroll
    for (int i = tid; i < G_DIM * D_DIM; i += 256) sIdx[i] = idx[i];

    #pragma unroll
    for (int r = 0; r < ROWS1; ++r) {
        const float4* src = (const float4*)(x + (size_t)(row0 + r) * E_DIM);
        float4* dst = (float4*)sX[r];
        dst[tid]       = src[tid];
        dst[tid + 256] = src[tid + 256];
    }
    __syncthreads();

    #pragma unroll
    for (int r = 0; r < ROWS1; ++r) {
        float* orow = out + (size_t)(row0 + r) * G_DIM * D_DIM;
        #pragma unroll
        for (int t = 0; t < 4; ++t) {
            const int j = (t * 256 + tid) * 4;       // 0..4095, float4-aligned
            float4 v = make_float4(sX[r][sIdx[j]],     sX[r][sIdx[j + 1]],
                                   sX[r][sIdx[j + 2]], sX[r][sIdx[j + 3]]);
            *(float4*)(orow + j) = v;
        }
    }
}

// ---------------- pass 2: dense+gelu x2, residual, layernorm ----------------
__global__ __launch_bounds__(256) void ssb_compute_kernel(
    const float* __restrict__ W,
    const float* __restrict__ bias,
    const float* __restrict__ gamma,
    const float* __restrict__ beta,
    float* __restrict__ out)
{
    __shared__ float sBuf[BM * LDSW];   // gathered tile, then layer-0 activations

    const int g    = blockIdx.y;
    const int row0 = blockIdx.x * BM;
    const int tid  = threadIdx.x;
    const int tx   = tid & 15;   // cols 8*tx .. 8*tx+7
    const int ty   = tid >> 4;   // rows 4*ty .. 4*ty+3

    // ----- load this block's gathered tile (coalesced); keep residual in regs -----
    float gres[4][8];
    #pragma unroll
    for (int i = 0; i < 4; ++i) {
        const int r = 4 * ty + i;
        const float4* src = (const float4*)(out + ((size_t)(row0 + r) * G_DIM + g) * D_DIM + 8 * tx);
        const float4 a0 = src[0], a1 = src[1];
        gres[i][0] = a0.x; gres[i][1] = a0.y; gres[i][2] = a0.z; gres[i][3] = a0.w;
        gres[i][4] = a1.x; gres[i][5] = a1.y; gres[i][6] = a1.z; gres[i][7] = a1.w;
        float4* dst = (float4*)(sBuf + r * LDSW + 8 * tx);
        dst[0] = a0; dst[1] = a1;
    }
    __syncthreads();

    float acc[4][8];

    // ================= layer 0: sBuf -> gelu -> sBuf =================
    {
        const float* Wl = W + (size_t)(g * L_DIM + 0) * D_DIM * D_DIM;
        const float* bl = bias + (g * L_DIM + 0) * D_DIM;
        const float4 b0 = *(const float4*)(bl + 8 * tx);
        const float4 b1 = *(const float4*)(bl + 8 * tx + 4);
        #pragma unroll
        for (int i = 0; i < 4; ++i) {
            acc[i][0] = b0.x; acc[i][1] = b0.y; acc[i][2] = b0.z; acc[i][3] = b0.w;
            acc[i][4] = b1.x; acc[i][5] = b1.y; acc[i][6] = b1.z; acc[i][7] = b1.w;
        }
        for (int k4 = 0; k4 < D_DIM; k4 += 4) {
            float4 hv[4];
            #pragma unroll
            for (int i = 0; i < 4; ++i)
                hv[i] = *(const float4*)(sBuf + (4 * ty + i) * LDSW + k4);
            #pragma unroll
            for (int kk = 0; kk < 4; ++kk) {
                const float* wrow = Wl + (size_t)(k4 + kk) * D_DIM + 8 * tx;
                const float4 wa = *(const float4*)(wrow);
                const float4 wb = *(const float4*)(wrow + 4);
                #pragma unroll
                for (int i = 0; i < 4; ++i) {
                    const float h = (&hv[i].x)[kk];
                    acc[i][0] = fmaf(h, wa.x, acc[i][0]);
                    acc[i][1] = fmaf(h, wa.y, acc[i][1]);
                    acc[i][2] = fmaf(h, wa.z, acc[i][2]);
                    acc[i][3] = fmaf(h, wa.w, acc[i][3]);
                    acc[i][4] = fmaf(h, wb.x, acc[i][4]);
                    acc[i][5] = fmaf(h, wb.y, acc[i][5]);
                    acc[i][6] = fmaf(h, wb.z, acc[i][6]);
                    acc[i][7] = fmaf(h, wb.w, acc[i][7]);
                }
            }
        }
        __syncthreads();   // everyone done READING sBuf before overwrite
        #pragma unroll
        for (int i = 0; i < 4; ++i) {
            const int r = 4 * ty + i;
            float4* dst = (float4*)(sBuf + r * LDSW + 8 * tx);
            dst[0] = make_float4(gelu_exact(acc[i][0]), gelu_exact(acc[i][1]),
                                 gelu_exact(acc[i][2]), gelu_exact(acc[i][3]));
            dst[1] = make_float4(gelu_exact(acc[i][4]), gelu_exact(acc[i][5]),
                                 gelu_exact(acc[i][6]), gelu_exact(acc[i][7]));
        }
    }
    __syncthreads();

    // ================= layer 1 + epilogue =================
    {
        const float* Wl = W + (size_t)(g * L_DIM + 1) * D_DIM * D_DIM;
        const float* bl = bias + (g * L_DIM + 1) * D_DIM;
        const float4 b0 = *(const float4*)(bl + 8 * tx);
        const float4 b1 = *(const float4*)(bl + 8 * tx + 4);
        #pragma unroll
        for (int i = 0; i < 4; ++i) {
            acc[i][0] = b0.x; acc[i][1] = b0.y; acc[i][2] = b0.z; acc[i][3] = b0.w;
            acc[i][4] = b1.x; acc[i][5] = b1.y; acc[i][6] = b1.z; acc[i][7] = b1.w;
        }
        for (int k4 = 0; k4 < D_DIM; k4 += 4) {
            float4 hv[4];
            #pragma unroll
            for (int i = 0; i < 4; ++i)
                hv[i] = *(const float4*)(sBuf + (4 * ty + i) * LDSW + k4);
            #pragma unroll
            for (int kk = 0; kk < 4; ++kk) {
                const float* wrow = Wl + (size_t)(k4 + kk) * D_DIM + 8 * tx;
                const float4 wa = *(const float4*)(wrow);
                const float4 wb = *(const float4*)(wrow + 4);
                #pragma unroll
                for (int i = 0; i < 4; ++i) {
                    const float h = (&hv[i].x)[kk];
                    acc[i][0] = fmaf(h, wa.x, acc[i][0]);
                    acc[i][1] = fmaf(h, wa.y, acc[i][1]);
                    acc[i][2] = fmaf(h, wa.z, acc[i][2]);
                    acc[i][3] = fmaf(h, wa.w, acc[i][3]);
                    acc[i][4] = fmaf(h, wb.x, acc[i][4]);
                    acc[i][5] = fmaf(h, wb.y, acc[i][5]);
                    acc[i][6] = fmaf(h, wb.z, acc[i][6]);
                    acc[i][7] = fmaf(h, wb.w, acc[i][7]);
                }
            }
        }
        // gelu + residual + LayerNorm (row reduce over the 16 tx lanes)
        const float4 gm0 = *(const float4*)(gamma + g * D_DIM + 8 * tx);
        const float4 gm1 = *(const float4*)(gamma + g * D_DIM + 8 * tx + 4);
        const float4 bt0 = *(const float4*)(beta  + g * D_DIM + 8 * tx);
        const float4 bt1 = *(const float4*)(beta  + g * D_DIM + 8 * tx + 4);
        #pragma unroll
        for (int i = 0; i < 4; ++i) {
            const int r = 4 * ty + i;
            float v[8];
            #pragma unroll
            for (int c = 0; c < 8; ++c) v[c] = gelu_exact(acc[i][c]) + gres[i][c];

            float s = 0.f;
            #pragma unroll
            for (int c = 0; c < 8; ++c) s += v[c];
            #pragma unroll
            for (int m = 8; m >= 1; m >>= 1) s += __shfl_xor(s, m, 64);
            const float mu = s * (1.0f / 128.0f);

            float q = 0.f;
            #pragma unroll
            for (int c = 0; c < 8; ++c) { const float d = v[c] - mu; q += d * d; }
            #pragma unroll
            for (int m = 8; m >= 1; m >>= 1) q += __shfl_xor(q, m, 64);
            const float rstd = rsqrtf(q * (1.0f / 128.0f) + LN_EPS);

            float o[8];
            o[0] = (v[0] - mu) * rstd * gm0.x + bt0.x;
            o[1] = (v[1] - mu) * rstd * gm0.y + bt0.y;
            o[2] = (v[2] - mu) * rstd * gm0.z + bt0.z;
            o[3] = (v[3] - mu) * rstd * gm0.w + bt0.w;
            o[4] = (v[4] - mu) * rstd * gm1.x + bt1.x;
            o[5] = (v[5] - mu) * rstd * gm1.y + bt1.y;
            o[6] = (v[6] - mu) * rstd * gm1.z + bt1.z;
            o[7] = (v[7] - mu) * rstd * gm1.w + bt1.w;

            float4* op = (float4*)(out + ((size_t)(row0 + r) * G_DIM + g) * D_DIM + 8 * tx);
            op[0] = make_float4(o[0], o[1], o[2], o[3]);
            op[1] = make_float4(o[4], o[5], o[6], o[7]);
        }
    }
}

extern "C" void kernel_launch(void* const* d_in, const int* in_sizes, int n_in,
                              void* d_out, int out_size, void* d_ws, size_t ws_size,
                              hipStream_t stream) {
    const float* x     = (const float*)d_in[0];
    const int*   idx   = (const int*)d_in[1];
    const float* W     = (const float*)d_in[2];
    const float* b     = (const float*)d_in[3];
    const float* gamma = (const float*)d_in[4];
    const float* beta  = (const float*)d_in[5];
    float* out = (float*)d_out;

    const int B = in_sizes[0] / E_DIM;   // 16384

    ssb_gather_kernel<<<dim3(B / ROWS1), 256, 0, stream>>>(x, idx, out);
    ssb_compute_kernel<<<dim3(B / BM, G_DIM), 256, 0, stream>>>(W, b, gamma, beta, out);
}

// Round 3
// 350.967 us; speedup vs baseline: 2.4165x; 2.1379x over previous
//
#include <hip/hip_runtime.h>
#include <math.h>
#include <stdint.h>

// StructuralSparseBlock: gather -> (Dense 128x128 + exact GELU) x2 -> +residual -> LayerNorm
// B=16384, E=2048, G=32, D=128, L=2, fp32 in/out.
// 3 kernels: (0) W -> bf16 MFMA B-fragment layout in d_ws
//            (1) gather x into d_out [B,G,D] (each x row read once)
//            (2) MFMA bf16 dense stack + residual + LayerNorm, in-place on d_out

constexpr int E_DIM = 2048;
constexpr int G_DIM = 32;
constexpr int D_DIM = 128;
constexpr float LN_EPS = 1e-3f;

constexpr int ROWS1 = 4;     // rows per block, gather pass
constexpr int BM    = 64;    // rows per block, compute pass
constexpr int AW    = 136;   // sAct row stride (shorts): +8 pad -> 4-bank/row shift -> 2-way (free)

typedef float f32x4  __attribute__((ext_vector_type(4)));
typedef short bf16x8 __attribute__((ext_vector_type(8)));

__device__ __forceinline__ short f2bf(float f) {   // RNE float->bf16 (finite inputs)
    uint32_t u = __builtin_bit_cast(uint32_t, f);
    uint32_t r = (u + 0x7fffu + ((u >> 16) & 1u)) >> 16;
    return (short)r;
}
__device__ __forceinline__ float bf2f(short s) {
    uint32_t u = ((uint32_t)(uint16_t)s) << 16;
    return __builtin_bit_cast(float, u);
}
__device__ __forceinline__ float gelu_exact(float v) {
    return 0.5f * v * (1.0f + erff(v * 0.70710678118654752f));
}

// ---------------- kernel 0: W[g][l][k][n] fp32 -> bf16 B-fragment layout ----------------
// frag layout: ((gl*8 + nt)*4 + ks)*512 + lane*8 + j  <=>  W[ks*32 + 8*(lane>>4) + j][nt*16 + (lane&15)]
__global__ __launch_bounds__(256) void ssb_wprep_kernel(
    const float* __restrict__ W, short* __restrict__ Wf)
{
    const int t    = blockIdx.x * 256 + threadIdx.x;   // 0 .. 131071
    const int lane = t & 63;
    const int ks   = (t >> 6) & 3;
    const int nt   = (t >> 8) & 7;
    const int gl   = t >> 11;                          // 0..63 = g*2+l
    const float* Wl = W + (size_t)gl * D_DIM * D_DIM;
    const int n  = nt * 16 + (lane & 15);
    const int k0 = ks * 32 + ((lane >> 4) << 3);
    short* dst = Wf + (size_t)t * 8;
    #pragma unroll
    for (int j = 0; j < 8; ++j) dst[j] = f2bf(Wl[(size_t)(k0 + j) * D_DIM + n]);
}

// ---------------- kernel 1: gather all groups, x rows staged in LDS ----------------
__global__ __launch_bounds__(256) void ssb_gather_kernel(
    const float* __restrict__ x,
    const int*   __restrict__ idx,
    float* __restrict__ out)
{
    __shared__ float sX[ROWS1][E_DIM];     // 32 KB
    __shared__ int   sIdx[G_DIM * D_DIM];  // 16 KB

    const int tid  = threadIdx.x;
    const int row0 = blockIdx.x * ROWS1;

    for (int i = tid; i < G_DIM * D_DIM; i += 256) sIdx[i] = idx[i];

    #pragma unroll
    for (int r = 0; r < ROWS1; ++r) {
        const float4* src = (const float4*)(x + (size_t)(row0 + r) * E_DIM);
        float4* dst = (float4*)sX[r];
        dst[tid]       = src[tid];
        dst[tid + 256] = src[tid + 256];
    }
    __syncthreads();

    #pragma unroll
    for (int r = 0; r < ROWS1; ++r) {
        float* orow = out + (size_t)(row0 + r) * G_DIM * D_DIM;
        #pragma unroll
        for (int t = 0; t < 4; ++t) {
            const int j = (t * 256 + tid) * 4;
            float4 v = make_float4(sX[r][sIdx[j]],     sX[r][sIdx[j + 1]],
                                   sX[r][sIdx[j + 2]], sX[r][sIdx[j + 3]]);
            *(float4*)(orow + j) = v;
        }
    }
}

// ---------------- kernel 2: MFMA dense+gelu x2, residual, layernorm ----------------
__global__ __launch_bounds__(256) void ssb_mfma_kernel(
    const short* __restrict__ Wf,
    const float* __restrict__ bias,
    const float* __restrict__ gamma,
    const float* __restrict__ beta,
    float* __restrict__ out)
{
    __shared__ __align__(16) short sAct[BM * AW];        // 17.4 KB bf16 activation tile
    __shared__ __align__(16) short sW[D_DIM * D_DIM];    // 32 KB, one layer's W fragments

    const int g    = blockIdx.y;
    const int row0 = blockIdx.x * BM;
    const int tid  = threadIdx.x;
    const int tx   = tid & 15;
    const int ty   = tid >> 4;
    const int lane = tid & 63;
    const int wv   = tid >> 6;

    // phase 0: load this block's gathered fp32 tile (coalesced), convert -> bf16 LDS
    #pragma unroll
    for (int i = 0; i < 4; ++i) {
        const int r = 4 * ty + i;
        const float4* src = (const float4*)(out + ((size_t)(row0 + r) * G_DIM + g) * D_DIM + 8 * tx);
        const float4 a0 = src[0], a1 = src[1];
        bf16x8 p;
        p[0] = f2bf(a0.x); p[1] = f2bf(a0.y); p[2] = f2bf(a0.z); p[3] = f2bf(a0.w);
        p[4] = f2bf(a1.x); p[5] = f2bf(a1.y); p[6] = f2bf(a1.z); p[7] = f2bf(a1.w);
        *(bf16x8*)(sAct + r * AW + 8 * tx) = p;
    }
    // stage W layer 0
    {
        const uint4* src = (const uint4*)(Wf + (size_t)(g * 2 + 0) * (D_DIM * D_DIM));
        uint4* dst = (uint4*)sW;
        #pragma unroll
        for (int i = 0; i < 8; ++i) dst[tid + 256 * i] = src[tid + 256 * i];
    }
    __syncthreads();

    const int arow = wv * 16 + (lane & 15);         // A-fragment row
    const int kq   = (lane >> 4) << 3;              // k offset within 32-chunk
    const int ccol = lane & 15;                     // C/D col offset
    const int crow = wv * 16 + ((lane >> 4) << 2);  // C/D row base

    f32x4 acc[8];

    // ---------------- layer 0 ----------------
    {
        const float* bl = bias + (g * 2 + 0) * D_DIM;
        #pragma unroll
        for (int nt = 0; nt < 8; ++nt) {
            const float b = bl[nt * 16 + ccol];
            acc[nt] = (f32x4){b, b, b, b};
        }
        #pragma unroll
        for (int ks = 0; ks < 4; ++ks) {
            const bf16x8 a = *(const bf16x8*)(sAct + arow * AW + ks * 32 + kq);
            #pragma unroll
            for (int nt = 0; nt < 8; ++nt) {
                const bf16x8 bfr = *(const bf16x8*)(sW + (nt * 4 + ks) * 512 + lane * 8);
                acc[nt] = __builtin_amdgcn_mfma_f32_16x16x32_bf16(a, bfr, acc[nt], 0, 0, 0);
            }
        }
    }
    __syncthreads();   // all waves done reading sW before restage

    // GELU writeback to sAct (each wave writes only its own 16 rows) + stage W layer 1
    #pragma unroll
    for (int nt = 0; nt < 8; ++nt)
        #pragma unroll
        for (int j = 0; j < 4; ++j)
            sAct[(crow + j) * AW + nt * 16 + ccol] = f2bf(gelu_exact(acc[nt][j]));
    {
        const uint4* src = (const uint4*)(Wf + (size_t)(g * 2 + 1) * (D_DIM * D_DIM));
        uint4* dst = (uint4*)sW;
        #pragma unroll
        for (int i = 0; i < 8; ++i) dst[tid + 256 * i] = src[tid + 256 * i];
    }
    __syncthreads();

    // ---------------- layer 1 ----------------
    {
        const float* bl = bias + (g * 2 + 1) * D_DIM;
        #pragma unroll
        for (int nt = 0; nt < 8; ++nt) {
            const float b = bl[nt * 16 + ccol];
            acc[nt] = (f32x4){b, b, b, b};
        }
        #pragma unroll
        for (int ks = 0; ks < 4; ++ks) {
            const bf16x8 a = *(const bf16x8*)(sAct + arow * AW + ks * 32 + kq);
            #pragma unroll
            for (int nt = 0; nt < 8; ++nt) {
                const bf16x8 bfr = *(const bf16x8*)(sW + (nt * 4 + ks) * 512 + lane * 8);
                acc[nt] = __builtin_amdgcn_mfma_f32_16x16x32_bf16(a, bfr, acc[nt], 0, 0, 0);
            }
        }
    }

    // ---------------- epilogue: gelu + residual + LayerNorm + store ----------------
    float v[8][4];
    #pragma unroll
    for (int nt = 0; nt < 8; ++nt)
        #pragma unroll
        for (int j = 0; j < 4; ++j) {
            const size_t r = (size_t)(row0 + crow + j);
            const float res = out[(r * G_DIM + g) * D_DIM + nt * 16 + ccol];
            v[nt][j] = gelu_exact(acc[nt][j]) + res;
        }

    float mu[4], rs[4];
    #pragma unroll
    for (int j = 0; j < 4; ++j) {
        float s = 0.f;
        #pragma unroll
        for (int nt = 0; nt < 8; ++nt) s += v[nt][j];
        #pragma unroll
        for (int m = 8; m >= 1; m >>= 1) s += __shfl_xor(s, m, 64);
        mu[j] = s * (1.0f / 128.0f);
        float q = 0.f;
        #pragma unroll
        for (int nt = 0; nt < 8; ++nt) { const float d = v[nt][j] - mu[j]; q += d * d; }
        #pragma unroll
        for (int m = 8; m >= 1; m >>= 1) q += __shfl_xor(q, m, 64);
        rs[j] = rsqrtf(q * (1.0f / 128.0f) + LN_EPS);
    }

    #pragma unroll
    for (int nt = 0; nt < 8; ++nt) {
        const float gm = gamma[g * D_DIM + nt * 16 + ccol];
        const float bt = beta [g * D_DIM + nt * 16 + ccol];
        #pragma unroll
        for (int j = 0; j < 4; ++j) {
            const size_t r = (size_t)(row0 + crow + j);
            out[(r * G_DIM + g) * D_DIM + nt * 16 + ccol] =
                (v[nt][j] - mu[j]) * rs[j] * gm + bt;
        }
    }
}

extern "C" void kernel_launch(void* const* d_in, const int* in_sizes, int n_in,
                              void* d_out, int out_size, void* d_ws, size_t ws_size,
                              hipStream_t stream) {
    const float* x     = (const float*)d_in[0];
    const int*   idx   = (const int*)d_in[1];
    const float* W     = (const float*)d_in[2];
    const float* b     = (const float*)d_in[3];
    const float* gamma = (const float*)d_in[4];
    const float* beta  = (const float*)d_in[5];
    float* out = (float*)d_out;
    short* Wf  = (short*)d_ws;            // 2 MB bf16 fragment-layout W

    const int B = in_sizes[0] / E_DIM;    // 16384

    ssb_wprep_kernel<<<dim3(512), 256, 0, stream>>>(W, Wf);
    ssb_gather_kernel<<<dim3(B / ROWS1), 256, 0, stream>>>(x, idx, out);
    ssb_mfma_kernel<<<dim3(B / BM, G_DIM), 256, 0, stream>>>(Wf, b, gamma, beta, out);
}

// Round 4
// 306.325 us; speedup vs baseline: 2.7687x; 1.1457x over previous
//
#include <hip/hip_runtime.h>
#include <math.h>
#include <stdint.h>

// StructuralSparseBlock: gather -> (Dense 128x128 + GELU) x2 -> +residual -> LayerNorm
// B=16384, E=2048, G=32, D=128, L=2, fp32 in/out.
// 3 kernels: (0) W -> bf16 MFMA B-fragment layout in d_ws
//            (1) gather x into d_out [B,G,D] (each x row read once)
//            (2) MFMA bf16 dense stack + residual + LayerNorm, in-place on d_out
//                (W fragments read straight from global: L1/L2-hot, no sW LDS)

constexpr int E_DIM = 2048;
constexpr int G_DIM = 32;
constexpr int D_DIM = 128;
constexpr float LN_EPS = 1e-3f;

constexpr int ROWS1 = 4;     // rows per block, gather pass
constexpr int BM    = 64;    // rows per block, compute pass
constexpr int AW    = 136;   // sAct row stride (shorts): +8 pad -> uniform bank spread on b128

typedef float f32x4  __attribute__((ext_vector_type(4)));
typedef short bf16x8 __attribute__((ext_vector_type(8)));

__device__ __forceinline__ short f2bf(float f) {   // RNE float->bf16 (finite inputs)
    uint32_t u = __builtin_bit_cast(uint32_t, f);
    uint32_t r = (u + 0x7fffu + ((u >> 16) & 1u)) >> 16;
    return (short)r;
}
// tanh-form GELU on HW exp2/rcp: max |diff vs exact| ~3e-3, ~8 VALU instrs
__device__ __forceinline__ float gelu_fast(float x) {
    const float x2 = x * x;
    const float z  = 2.30220817f * x * fmaf(0.044715f, x2, 1.0f);
    const float e  = __builtin_amdgcn_exp2f(-z);
    return x * __builtin_amdgcn_rcpf(1.0f + e);
}

// ---------------- kernel 0: W[g][l][k][n] fp32 -> bf16 B-fragment layout ----------------
// frag layout: ((gl*8 + nt)*4 + ks)*512 + lane*8 + j  <=>  W[ks*32 + 8*(lane>>4) + j][nt*16 + (lane&15)]
__global__ __launch_bounds__(256) void ssb_wprep_kernel(
    const float* __restrict__ W, short* __restrict__ Wf)
{
    const int t    = blockIdx.x * 256 + threadIdx.x;   // 0 .. 131071
    const int lane = t & 63;
    const int ks   = (t >> 6) & 3;
    const int nt   = (t >> 8) & 7;
    const int gl   = t >> 11;                          // 0..63 = g*2+l
    const float* Wl = W + (size_t)gl * D_DIM * D_DIM;
    const int n  = nt * 16 + (lane & 15);
    const int k0 = ks * 32 + ((lane >> 4) << 3);
    short* dst = Wf + (size_t)t * 8;
    #pragma unroll
    for (int j = 0; j < 8; ++j) dst[j] = f2bf(Wl[(size_t)(k0 + j) * D_DIM + n]);
}

// ---------------- kernel 1: gather all groups, x rows staged in LDS ----------------
__global__ __launch_bounds__(256) void ssb_gather_kernel(
    const float* __restrict__ x,
    const int*   __restrict__ idx,
    float* __restrict__ out)
{
    __shared__ float sX[ROWS1][E_DIM];     // 32 KB
    __shared__ int   sIdx[G_DIM * D_DIM];  // 16 KB

    const int tid  = threadIdx.x;
    const int row0 = blockIdx.x * ROWS1;

    for (int i = tid; i < G_DIM * D_DIM; i += 256) sIdx[i] = idx[i];

    #pragma unroll
    for (int r = 0; r < ROWS1; ++r) {
        const float4* src = (const float4*)(x + (size_t)(row0 + r) * E_DIM);
        float4* dst = (float4*)sX[r];
        dst[tid]       = src[tid];
        dst[tid + 256] = src[tid + 256];
    }
    __syncthreads();

    #pragma unroll
    for (int r = 0; r < ROWS1; ++r) {
        float* orow = out + (size_t)(row0 + r) * G_DIM * D_DIM;
        #pragma unroll
        for (int t = 0; t < 4; ++t) {
            const int j = (t * 256 + tid) * 4;
            float4 v = make_float4(sX[r][sIdx[j]],     sX[r][sIdx[j + 1]],
                                   sX[r][sIdx[j + 2]], sX[r][sIdx[j + 3]]);
            *(float4*)(orow + j) = v;
        }
    }
}

// ---------------- kernel 2: MFMA dense+gelu x2, residual, layernorm ----------------
__global__ __launch_bounds__(256) void ssb_mfma_kernel(
    const short* __restrict__ Wf,
    const float* __restrict__ bias,
    const float* __restrict__ gamma,
    const float* __restrict__ beta,
    float* __restrict__ out)
{
    __shared__ __align__(16) short sAct[BM * AW];   // 17.4 KB bf16 activation tile

    const int g    = blockIdx.y;
    const int row0 = blockIdx.x * BM;
    const int tid  = threadIdx.x;
    const int tx   = tid & 15;
    const int ty   = tid >> 4;
    const int lane = tid & 63;
    const int wv   = tid >> 6;

    // phase 0: load this block's gathered fp32 tile (coalesced), convert -> bf16 LDS
    #pragma unroll
    for (int i = 0; i < 4; ++i) {
        const int r = 4 * ty + i;
        const float4* src = (const float4*)(out + ((size_t)(row0 + r) * G_DIM + g) * D_DIM + 8 * tx);
        const float4 a0 = src[0], a1 = src[1];
        bf16x8 p;
        p[0] = f2bf(a0.x); p[1] = f2bf(a0.y); p[2] = f2bf(a0.z); p[3] = f2bf(a0.w);
        p[4] = f2bf(a1.x); p[5] = f2bf(a1.y); p[6] = f2bf(a1.z); p[7] = f2bf(a1.w);
        *(bf16x8*)(sAct + r * AW + 8 * tx) = p;
    }
    __syncthreads();

    const int arow = wv * 16 + (lane & 15);         // A-fragment row (own wave's strip)
    const int kq   = (lane >> 4) << 3;              // k offset within 32-chunk
    const int ccol = lane & 15;                     // C/D col offset
    const int crow = wv * 16 + ((lane >> 4) << 2);  // C/D row base (same strip)

    const short* Wg0 = Wf + (size_t)(g * 2 + 0) * (D_DIM * D_DIM);
    const short* Wg1 = Wf + (size_t)(g * 2 + 1) * (D_DIM * D_DIM);

    f32x4 acc[8];

    // ---------------- layer 0 ----------------
    {
        const float* bl = bias + (g * 2 + 0) * D_DIM;
        #pragma unroll
        for (int nt = 0; nt < 8; ++nt) {
            const float b = bl[nt * 16 + ccol];
            acc[nt] = (f32x4){b, b, b, b};
        }
        #pragma unroll
        for (int ks = 0; ks < 4; ++ks) {
            const bf16x8 a = *(const bf16x8*)(sAct + arow * AW + ks * 32 + kq);
            #pragma unroll
            for (int nt = 0; nt < 8; ++nt) {
                const bf16x8 bfr = *(const bf16x8*)(Wg0 + (nt * 4 + ks) * 512 + lane * 8);
                acc[nt] = __builtin_amdgcn_mfma_f32_16x16x32_bf16(a, bfr, acc[nt], 0, 0, 0);
            }
        }
    }
    __syncthreads();   // safety: phase separation before sAct overwrite

    // GELU writeback to sAct (each wave writes only its own strip's rows)
    #pragma unroll
    for (int nt = 0; nt < 8; ++nt)
        #pragma unroll
        for (int j = 0; j < 4; ++j)
            sAct[(crow + j) * AW + nt * 16 + ccol] = f2bf(gelu_fast(acc[nt][j]));
    __syncthreads();

    // ---------------- layer 1 ----------------
    {
        const float* bl = bias + (g * 2 + 1) * D_DIM;
        #pragma unroll
        for (int nt = 0; nt < 8; ++nt) {
            const float b = bl[nt * 16 + ccol];
            acc[nt] = (f32x4){b, b, b, b};
        }
        #pragma unroll
        for (int ks = 0; ks < 4; ++ks) {
            const bf16x8 a = *(const bf16x8*)(sAct + arow * AW + ks * 32 + kq);
            #pragma unroll
            for (int nt = 0; nt < 8; ++nt) {
                const bf16x8 bfr = *(const bf16x8*)(Wg1 + (nt * 4 + ks) * 512 + lane * 8);
                acc[nt] = __builtin_amdgcn_mfma_f32_16x16x32_bf16(a, bfr, acc[nt], 0, 0, 0);
            }
        }
    }

    // ---------------- epilogue: gelu + residual + LayerNorm + store ----------------
    float v[8][4];
    #pragma unroll
    for (int nt = 0; nt < 8; ++nt)
        #pragma unroll
        for (int j = 0; j < 4; ++j) {
            const size_t r = (size_t)(row0 + crow + j);
            const float res = out[(r * G_DIM + g) * D_DIM + nt * 16 + ccol];
            v[nt][j] = gelu_fast(acc[nt][j]) + res;
        }

    float mu[4], rs[4];
    #pragma unroll
    for (int j = 0; j < 4; ++j) {
        float s = 0.f;
        #pragma unroll
        for (int nt = 0; nt < 8; ++nt) s += v[nt][j];
        #pragma unroll
        for (int m = 8; m >= 1; m >>= 1) s += __shfl_xor(s, m, 64);
        mu[j] = s * (1.0f / 128.0f);
        float q = 0.f;
        #pragma unroll
        for (int nt = 0; nt < 8; ++nt) { const float d = v[nt][j] - mu[j]; q += d * d; }
        #pragma unroll
        for (int m = 8; m >= 1; m >>= 1) q += __shfl_xor(q, m, 64);
        rs[j] = rsqrtf(q * (1.0f / 128.0f) + LN_EPS);
    }

    #pragma unroll
    for (int nt = 0; nt < 8; ++nt) {
        const float gm = gamma[g * D_DIM + nt * 16 + ccol];
        const float bt = beta [g * D_DIM + nt * 16 + ccol];
        #pragma unroll
        for (int j = 0; j < 4; ++j) {
            const size_t r = (size_t)(row0 + crow + j);
            out[(r * G_DIM + g) * D_DIM + nt * 16 + ccol] =
                (v[nt][j] - mu[j]) * rs[j] * gm + bt;
        }
    }
}

extern "C" void kernel_launch(void* const* d_in, const int* in_sizes, int n_in,
                              void* d_out, int out_size, void* d_ws, size_t ws_size,
                              hipStream_t stream) {
    const float* x     = (const float*)d_in[0];
    const int*   idx   = (const int*)d_in[1];
    const float* W     = (const float*)d_in[2];
    const float* b     = (const float*)d_in[3];
    const float* gamma = (const float*)d_in[4];
    const float* beta  = (const float*)d_in[5];
    float* out = (float*)d_out;
    short* Wf  = (short*)d_ws;            // 2 MB bf16 fragment-layout W

    const int B = in_sizes[0] / E_DIM;    // 16384

    ssb_wprep_kernel<<<dim3(512), 256, 0, stream>>>(W, Wf);
    ssb_gather_kernel<<<dim3(B / ROWS1), 256, 0, stream>>>(x, idx, out);
    ssb_mfma_kernel<<<dim3(B / BM, G_DIM), 256, 0, stream>>>(Wf, b, gamma, beta, out);
}

// Round 5
// 274.684 us; speedup vs baseline: 3.0876x; 1.1152x over previous
//
#include <hip/hip_runtime.h>
#include <math.h>
#include <stdint.h>

// StructuralSparseBlock: gather -> (Dense 128x128 + GELU) x2 -> +residual -> LayerNorm
// B=16384, E=2048, G=32, D=128, L=2, fp32 in/out.
// 3 kernels: (0) W -> bf16 MFMA B-fragment layout in d_ws
//            (1) gather x into bf16 [B,G,D] in d_ws (fallback: fp32 in d_out)
//            (2) barrier-free MFMA dense stack + residual + LayerNorm -> d_out
//                All LDS strips are wave-private; waves run as independent
//                16-row pipelines (no __syncthreads anywhere in kernel 2).

constexpr int E_DIM = 2048;
constexpr int G_DIM = 32;
constexpr int D_DIM = 128;
constexpr float LN_EPS = 1e-3f;

constexpr int ROWS1 = 4;     // rows per block, gather pass
constexpr int BM    = 64;    // rows per block, compute pass (4 waves x 16 rows)
constexpr int AW    = 136;   // sAct row stride in shorts (+8 pad)

typedef float f32x4  __attribute__((ext_vector_type(4)));
typedef short bf16x8 __attribute__((ext_vector_type(8)));

__device__ __forceinline__ short f2bf(float f) {   // RNE float->bf16 (finite inputs)
    uint32_t u = __builtin_bit_cast(uint32_t, f);
    uint32_t r = (u + 0x7fffu + ((u >> 16) & 1u)) >> 16;
    return (short)r;
}
__device__ __forceinline__ float bf2f(short s) {
    uint32_t u = ((uint32_t)(uint16_t)s) << 16;
    return __builtin_bit_cast(float, u);
}
// tanh-form GELU on HW exp2/rcp: max |diff vs exact| ~3e-3
__device__ __forceinline__ float gelu_fast(float x) {
    const float x2 = x * x;
    const float z  = 2.30220817f * x * fmaf(0.044715f, x2, 1.0f);
    const float e  = __builtin_amdgcn_exp2f(-z);
    return x * __builtin_amdgcn_rcpf(1.0f + e);
}

// ---------------- kernel 0: W[g][l][k][n] fp32 -> bf16 B-fragment layout ----------------
// frag layout: ((gl*8 + nt)*4 + ks)*512 + lane*8 + j  <=>  W[ks*32 + 8*(lane>>4) + j][nt*16 + (lane&15)]
__global__ __launch_bounds__(256) void ssb_wprep_kernel(
    const float* __restrict__ W, short* __restrict__ Wf)
{
    const int t    = blockIdx.x * 256 + threadIdx.x;   // 0 .. 131071
    const int lane = t & 63;
    const int ks   = (t >> 6) & 3;
    const int nt   = (t >> 8) & 7;
    const int gl   = t >> 11;                          // 0..63 = g*2+l
    const float* Wl = W + (size_t)gl * D_DIM * D_DIM;
    const int n  = nt * 16 + (lane & 15);
    const int k0 = ks * 32 + ((lane >> 4) << 3);
    short* dst = Wf + (size_t)t * 8;
    #pragma unroll
    for (int j = 0; j < 8; ++j) dst[j] = f2bf(Wl[(size_t)(k0 + j) * D_DIM + n]);
}

// ---------------- kernel 1: gather all groups, x rows staged in LDS ----------------
template<bool WS>
__global__ __launch_bounds__(256) void ssb_gather_kernel(
    const float* __restrict__ x,
    const int*   __restrict__ idx,
    float* __restrict__ outF,      // used when !WS (fp32 into d_out)
    short* __restrict__ outH)      // used when WS  (bf16 into d_ws)
{
    __shared__ float sX[ROWS1][E_DIM];     // 32 KB
    __shared__ int   sIdx[G_DIM * D_DIM];  // 16 KB

    const int tid  = threadIdx.x;
    const int row0 = blockIdx.x * ROWS1;

    for (int i = tid; i < G_DIM * D_DIM; i += 256) sIdx[i] = idx[i];

    #pragma unroll
    for (int r = 0; r < ROWS1; ++r) {
        const float4* src = (const float4*)(x + (size_t)(row0 + r) * E_DIM);
        float4* dst = (float4*)sX[r];
        dst[tid]       = src[tid];
        dst[tid + 256] = src[tid + 256];
    }
    __syncthreads();

    #pragma unroll
    for (int r = 0; r < ROWS1; ++r) {
        const size_t base = (size_t)(row0 + r) * G_DIM * D_DIM;
        #pragma unroll
        for (int t = 0; t < 4; ++t) {
            const int j = (t * 256 + tid) * 4;
            const float v0 = sX[r][sIdx[j]],     v1 = sX[r][sIdx[j + 1]];
            const float v2 = sX[r][sIdx[j + 2]], v3 = sX[r][sIdx[j + 3]];
            if (WS) {
                short4 v; v.x = f2bf(v0); v.y = f2bf(v1); v.z = f2bf(v2); v.w = f2bf(v3);
                *(short4*)(outH + base + j) = v;
            } else {
                *(float4*)(outF + base + j) = make_float4(v0, v1, v2, v3);
            }
        }
    }
}

// ---------------- kernel 2: barrier-free MFMA dense+gelu x2, residual, layernorm ----------------
template<bool WS>
__global__ __launch_bounds__(256, 4) void ssb_mfma_kernel(
    const short* __restrict__ Wf,
    const short* __restrict__ actH,    // WS: bf16 gathered [B][G][D]
    const float* __restrict__ bias,
    const float* __restrict__ gamma,
    const float* __restrict__ beta,
    float* __restrict__ out)
{
    __shared__ __align__(16) short sAct[BM * AW];   // 17 KB, 4 wave-private 16-row strips

    const int g    = blockIdx.y;
    const int tid  = threadIdx.x;
    const int lane = tid & 63;
    const int wv   = tid >> 6;
    const int q    = lane >> 4;          // quarter 0..3
    const int c16  = lane & 15;
    const size_t rbase = (size_t)blockIdx.x * BM + wv * 16;   // this wave's first row

    short* strip = sAct + wv * 16 * AW;  // wave-private

    // ---- phase 0: load own 16-row strip into LDS as bf16 ----
    #pragma unroll
    for (int i = 0; i < 4; ++i) {
        const int rl = 4 * q + i;
        const size_t off = ((rbase + rl) * G_DIM + g) * D_DIM + 8 * c16;
        bf16x8 p;
        if (WS) {
            p = *(const bf16x8*)(actH + off);
        } else {
            const float4* src = (const float4*)(out + off);
            const float4 a0 = src[0], a1 = src[1];
            p[0] = f2bf(a0.x); p[1] = f2bf(a0.y); p[2] = f2bf(a0.z); p[3] = f2bf(a0.w);
            p[4] = f2bf(a1.x); p[5] = f2bf(a1.y); p[6] = f2bf(a1.z); p[7] = f2bf(a1.w);
        }
        *(bf16x8*)(strip + rl * AW + 8 * c16) = p;
    }

    const short* Wg0 = Wf + (size_t)(g * 2 + 0) * (D_DIM * D_DIM);
    const short* Wg1 = Wf + (size_t)(g * 2 + 1) * (D_DIM * D_DIM);

    f32x4 acc[8];

    // ---- layer 0 (acc zero-init, bias folded into GELU) ----
    #pragma unroll
    for (int nt = 0; nt < 8; ++nt) acc[nt] = (f32x4){0.f, 0.f, 0.f, 0.f};
    #pragma unroll
    for (int ks = 0; ks < 4; ++ks) {
        const bf16x8 a = *(const bf16x8*)(strip + c16 * AW + ks * 32 + q * 8);
        #pragma unroll
        for (int nt = 0; nt < 8; ++nt) {
            const bf16x8 bfr = *(const bf16x8*)(Wg0 + (nt * 4 + ks) * 512 + lane * 8);
            acc[nt] = __builtin_amdgcn_mfma_f32_16x16x32_bf16(a, bfr, acc[nt], 0, 0, 0);
        }
    }

    // ---- GELU(acc + b0) -> own strip (wave-private, no barrier) ----
    {
        const float* bl0 = bias + (g * 2 + 0) * D_DIM;
        #pragma unroll
        for (int nt = 0; nt < 8; ++nt) {
            const float b0 = bl0[nt * 16 + c16];
            #pragma unroll
            for (int j = 0; j < 4; ++j)
                strip[(4 * q + j) * AW + nt * 16 + c16] = f2bf(gelu_fast(acc[nt][j] + b0));
        }
    }

    // ---- layer 1 ----
    #pragma unroll
    for (int nt = 0; nt < 8; ++nt) acc[nt] = (f32x4){0.f, 0.f, 0.f, 0.f};
    #pragma unroll
    for (int ks = 0; ks < 4; ++ks) {
        const bf16x8 a = *(const bf16x8*)(strip + c16 * AW + ks * 32 + q * 8);
        #pragma unroll
        for (int nt = 0; nt < 8; ++nt) {
            const bf16x8 bfr = *(const bf16x8*)(Wg1 + (nt * 4 + ks) * 512 + lane * 8);
            acc[nt] = __builtin_amdgcn_mfma_f32_16x16x32_bf16(a, bfr, acc[nt], 0, 0, 0);
        }
    }

    // ---- epilogue: v = gelu(acc+b1) + res; LN via s/s^2; recompute v on store ----
    const float* bl1 = bias + (g * 2 + 1) * D_DIM;
    float b1[8], gm[8], bt[8];
    #pragma unroll
    for (int nt = 0; nt < 8; ++nt) {
        b1[nt] = bl1[nt * 16 + c16];
        gm[nt] = gamma[g * D_DIM + nt * 16 + c16];
        bt[nt] = beta [g * D_DIM + nt * 16 + c16];
    }

    float s[4] = {0.f, 0.f, 0.f, 0.f}, s2[4] = {0.f, 0.f, 0.f, 0.f};
    #pragma unroll
    for (int nt = 0; nt < 8; ++nt) {
        #pragma unroll
        for (int j = 0; j < 4; ++j) {
            const size_t off = ((rbase + 4 * q + j) * G_DIM + g) * D_DIM + nt * 16 + c16;
            const float res = WS ? bf2f(actH[off]) : out[off];
            const float v = gelu_fast(acc[nt][j] + b1[nt]) + res;
            s[j] += v; s2[j] += v * v;
        }
    }
    float mu[4], rs[4];
    #pragma unroll
    for (int j = 0; j < 4; ++j) {
        #pragma unroll
        for (int m = 8; m >= 1; m >>= 1) {      // reduce over the 16 lanes of this quarter
            s[j]  += __shfl_xor(s[j],  m, 64);
            s2[j] += __shfl_xor(s2[j], m, 64);
        }
        mu[j] = s[j] * (1.0f / 128.0f);
        const float var = fmaxf(s2[j] * (1.0f / 128.0f) - mu[j] * mu[j], 0.f);
        rs[j] = rsqrtf(var + LN_EPS);
    }
    #pragma unroll
    for (int nt = 0; nt < 8; ++nt) {
        #pragma unroll
        for (int j = 0; j < 4; ++j) {
            const size_t off = ((rbase + 4 * q + j) * G_DIM + g) * D_DIM + nt * 16 + c16;
            const float res = WS ? bf2f(actH[off]) : out[off];
            const float v = gelu_fast(acc[nt][j] + b1[nt]) + res;
            out[off] = (v - mu[j]) * rs[j] * gm[nt] + bt[nt];
        }
    }
}

extern "C" void kernel_launch(void* const* d_in, const int* in_sizes, int n_in,
                              void* d_out, int out_size, void* d_ws, size_t ws_size,
                              hipStream_t stream) {
    const float* x     = (const float*)d_in[0];
    const int*   idx   = (const int*)d_in[1];
    const float* W     = (const float*)d_in[2];
    const float* b     = (const float*)d_in[3];
    const float* gamma = (const float*)d_in[4];
    const float* beta  = (const float*)d_in[5];
    float* out = (float*)d_out;
    short* Wf  = (short*)d_ws;                       // 2 MB bf16 fragment-layout W

    const int B = in_sizes[0] / E_DIM;               // 16384
    const size_t wfElems  = (size_t)G_DIM * 2 * D_DIM * D_DIM;       // 1 Mi shorts
    const size_t actElems = (size_t)B * G_DIM * D_DIM;               // 64 Mi shorts
    const bool useWs = ws_size >= (wfElems + actElems) * sizeof(short);
    short* actH = Wf + wfElems;

    ssb_wprep_kernel<<<dim3(512), 256, 0, stream>>>(W, Wf);
    if (useWs) {
        ssb_gather_kernel<true ><<<dim3(B / ROWS1), 256, 0, stream>>>(x, idx, out, actH);
        ssb_mfma_kernel <true ><<<dim3(B / BM, G_DIM), 256, 0, stream>>>(Wf, actH, b, gamma, beta, out);
    } else {
        ssb_gather_kernel<false><<<dim3(B / ROWS1), 256, 0, stream>>>(x, idx, out, actH);
        ssb_mfma_kernel <false><<<dim3(B / BM, G_DIM), 256, 0, stream>>>(Wf, actH, b, gamma, beta, out);
    }
}

// Round 6
// 256.498 us; speedup vs baseline: 3.3065x; 1.0709x over previous
//
#include <hip/hip_runtime.h>
#include <math.h>
#include <stdint.h>

// StructuralSparseBlock: gather -> (Dense 128x128 + GELU) x2 -> +residual -> LayerNorm
// B=16384, E=2048, G=32, D=128, L=2, fp32 in/out.
// 3 kernels: (0) W -> bf16 MFMA B-fragment layout in d_ws
//            (1) gather x into bf16 [B,G,D] in d_ws (fallback: fp32 in d_out)
//            (2) barrier-free MFMA dense stack + residual + LayerNorm -> d_out
//                Each wave owns 32 rows (two 16-row m-tiles) so every W fragment
//                load feeds 2 MFMAs; waves are independent (no __syncthreads).

constexpr int E_DIM = 2048;
constexpr int G_DIM = 32;
constexpr int D_DIM = 128;
constexpr float LN_EPS = 1e-3f;

constexpr int ROWS1 = 4;     // rows per block, gather pass
constexpr int BM    = 128;   // rows per block, compute pass (4 waves x 32 rows)
constexpr int AW    = 136;   // strip row stride in shorts (272 B = 17*16B: b128-aligned, 2-way banks)

typedef float f32x4  __attribute__((ext_vector_type(4)));
typedef short bf16x8 __attribute__((ext_vector_type(8)));

__device__ __forceinline__ short f2bf(float f) {   // RNE float->bf16 (finite inputs)
    uint32_t u = __builtin_bit_cast(uint32_t, f);
    uint32_t r = (u + 0x7fffu + ((u >> 16) & 1u)) >> 16;
    return (short)r;
}
__device__ __forceinline__ float bf2f(short s) {
    uint32_t u = ((uint32_t)(uint16_t)s) << 16;
    return __builtin_bit_cast(float, u);
}
// tanh-form GELU on HW exp2/rcp: max |diff vs exact| ~3e-3
__device__ __forceinline__ float gelu_fast(float x) {
    const float x2 = x * x;
    const float z  = 2.30220817f * x * fmaf(0.044715f, x2, 1.0f);
    const float e  = __builtin_amdgcn_exp2f(-z);
    return x * __builtin_amdgcn_rcpf(1.0f + e);
}

// ---------------- kernel 0: W[g][l][k][n] fp32 -> bf16 B-fragment layout ----------------
// frag layout: ((gl*8 + nt)*4 + ks)*512 + lane*8 + j  <=>  W[ks*32 + 8*(lane>>4) + j][nt*16 + (lane&15)]
__global__ __launch_bounds__(256) void ssb_wprep_kernel(
    const float* __restrict__ W, short* __restrict__ Wf)
{
    const int t    = blockIdx.x * 256 + threadIdx.x;   // 0 .. 131071
    const int lane = t & 63;
    const int ks   = (t >> 6) & 3;
    const int nt   = (t >> 8) & 7;
    const int gl   = t >> 11;                          // 0..63 = g*2+l
    const float* Wl = W + (size_t)gl * D_DIM * D_DIM;
    const int n  = nt * 16 + (lane & 15);
    const int k0 = ks * 32 + ((lane >> 4) << 3);
    short* dst = Wf + (size_t)t * 8;
    #pragma unroll
    for (int j = 0; j < 8; ++j) dst[j] = f2bf(Wl[(size_t)(k0 + j) * D_DIM + n]);
}

// ---------------- kernel 1: gather all groups, x rows staged in LDS ----------------
template<bool WS>
__global__ __launch_bounds__(256) void ssb_gather_kernel(
    const float* __restrict__ x,
    const int*   __restrict__ idx,
    float* __restrict__ outF,      // used when !WS (fp32 into d_out)
    short* __restrict__ outH)      // used when WS  (bf16 into d_ws)
{
    __shared__ float sX[ROWS1][E_DIM];     // 32 KB
    __shared__ int   sIdx[G_DIM * D_DIM];  // 16 KB

    const int tid  = threadIdx.x;
    const int row0 = blockIdx.x * ROWS1;

    for (int i = tid; i < G_DIM * D_DIM; i += 256) sIdx[i] = idx[i];

    #pragma unroll
    for (int r = 0; r < ROWS1; ++r) {
        const float4* src = (const float4*)(x + (size_t)(row0 + r) * E_DIM);
        float4* dst = (float4*)sX[r];
        dst[tid]       = src[tid];
        dst[tid + 256] = src[tid + 256];
    }
    __syncthreads();

    #pragma unroll
    for (int r = 0; r < ROWS1; ++r) {
        const size_t base = (size_t)(row0 + r) * G_DIM * D_DIM;
        #pragma unroll
        for (int t = 0; t < 4; ++t) {
            const int j = (t * 256 + tid) * 4;
            const float v0 = sX[r][sIdx[j]],     v1 = sX[r][sIdx[j + 1]];
            const float v2 = sX[r][sIdx[j + 2]], v3 = sX[r][sIdx[j + 3]];
            if (WS) {
                short4 v; v.x = f2bf(v0); v.y = f2bf(v1); v.z = f2bf(v2); v.w = f2bf(v3);
                *(short4*)(outH + base + j) = v;
            } else {
                *(float4*)(outF + base + j) = make_float4(v0, v1, v2, v3);
            }
        }
    }
}

// ---------------- kernel 2: barrier-free MFMA, 32 rows/wave ----------------
template<bool WS>
__global__ __launch_bounds__(256, 4) void ssb_mfma_kernel(
    const short* __restrict__ Wf,
    const short* __restrict__ actH,    // WS: bf16 gathered [B][G][D]
    const float* __restrict__ bias,
    const float* __restrict__ gamma,
    const float* __restrict__ beta,
    float* __restrict__ out)
{
    __shared__ __align__(16) short sAct[4][32 * AW];   // 34.8 KB, wave-private strips

    const int g    = blockIdx.y;
    const int tid  = threadIdx.x;
    const int lane = tid & 63;
    const int wv   = tid >> 6;
    const int q    = lane >> 4;          // quarter 0..3
    const int c16  = lane & 15;
    const size_t rbase = (size_t)blockIdx.x * BM + wv * 32;   // wave's first row

    short* strip = sAct[wv];

    // ---- phase 0: load own 32-row strip into LDS as bf16 (quarter q loads rows 8q..8q+7) ----
    #pragma unroll
    for (int i = 0; i < 8; ++i) {
        const int rl = 8 * q + i;
        const size_t off = ((rbase + rl) * G_DIM + g) * D_DIM + 8 * c16;
        bf16x8 p;
        if (WS) {
            p = *(const bf16x8*)(actH + off);
        } else {
            const float4* src = (const float4*)(out + off);
            const float4 a0 = src[0], a1 = src[1];
            p[0] = f2bf(a0.x); p[1] = f2bf(a0.y); p[2] = f2bf(a0.z); p[3] = f2bf(a0.w);
            p[4] = f2bf(a1.x); p[5] = f2bf(a1.y); p[6] = f2bf(a1.z); p[7] = f2bf(a1.w);
        }
        *(bf16x8*)(strip + rl * AW + 8 * c16) = p;
    }

    const short* Wg0 = Wf + (size_t)(g * 2 + 0) * (D_DIM * D_DIM);
    const short* Wg1 = Wf + (size_t)(g * 2 + 1) * (D_DIM * D_DIM);

    f32x4 acc0[8], acc1[8];

    // ---- layer 0 ----
    #pragma unroll
    for (int nt = 0; nt < 8; ++nt) { acc0[nt] = (f32x4){0,0,0,0}; acc1[nt] = (f32x4){0,0,0,0}; }
    #pragma unroll
    for (int ks = 0; ks < 4; ++ks) {
        const bf16x8 a0 = *(const bf16x8*)(strip + (     c16) * AW + ks * 32 + q * 8);
        const bf16x8 a1 = *(const bf16x8*)(strip + (16 + c16) * AW + ks * 32 + q * 8);
        #pragma unroll
        for (int nt = 0; nt < 8; ++nt) {
            const bf16x8 bfr = *(const bf16x8*)(Wg0 + (nt * 4 + ks) * 512 + lane * 8);
            acc0[nt] = __builtin_amdgcn_mfma_f32_16x16x32_bf16(a0, bfr, acc0[nt], 0, 0, 0);
            acc1[nt] = __builtin_amdgcn_mfma_f32_16x16x32_bf16(a1, bfr, acc1[nt], 0, 0, 0);
        }
    }

    // ---- GELU(acc + b0) -> own strip (wave-private, no barrier) ----
    {
        const float* bl0 = bias + (g * 2 + 0) * D_DIM;
        #pragma unroll
        for (int nt = 0; nt < 8; ++nt) {
            const float b0 = bl0[nt * 16 + c16];
            #pragma unroll
            for (int j = 0; j < 4; ++j) {
                strip[(     4 * q + j) * AW + nt * 16 + c16] = f2bf(gelu_fast(acc0[nt][j] + b0));
                strip[(16 + 4 * q + j) * AW + nt * 16 + c16] = f2bf(gelu_fast(acc1[nt][j] + b0));
            }
        }
    }

    // ---- layer 1 ----
    #pragma unroll
    for (int nt = 0; nt < 8; ++nt) { acc0[nt] = (f32x4){0,0,0,0}; acc1[nt] = (f32x4){0,0,0,0}; }
    #pragma unroll
    for (int ks = 0; ks < 4; ++ks) {
        const bf16x8 a0 = *(const bf16x8*)(strip + (     c16) * AW + ks * 32 + q * 8);
        const bf16x8 a1 = *(const bf16x8*)(strip + (16 + c16) * AW + ks * 32 + q * 8);
        #pragma unroll
        for (int nt = 0; nt < 8; ++nt) {
            const bf16x8 bfr = *(const bf16x8*)(Wg1 + (nt * 4 + ks) * 512 + lane * 8);
            acc0[nt] = __builtin_amdgcn_mfma_f32_16x16x32_bf16(a0, bfr, acc0[nt], 0, 0, 0);
            acc1[nt] = __builtin_amdgcn_mfma_f32_16x16x32_bf16(a1, bfr, acc1[nt], 0, 0, 0);
        }
    }

    // ---- epilogue: v = gelu(acc+b1) + res; LN via s/s^2; recompute v on store ----
    const float* bl1 = bias + (g * 2 + 1) * D_DIM;
    float b1[8], gm[8], bt[8];
    #pragma unroll
    for (int nt = 0; nt < 8; ++nt) {
        b1[nt] = bl1[nt * 16 + c16];
        gm[nt] = gamma[g * D_DIM + nt * 16 + c16];
        bt[nt] = beta [g * D_DIM + nt * 16 + c16];
    }

    auto epilogue = [&](const f32x4* acc, int mt) {
        const size_t r0 = (rbase + mt * 16 + 4 * q) * (size_t)(G_DIM * D_DIM) + (size_t)g * D_DIM + c16;
        const short* rp = actH + r0;   // WS residual base (row stride 4096 shorts)
        const float* fp = out  + r0;   // !WS residual base
        float s[4] = {0,0,0,0}, s2[4] = {0,0,0,0};
        #pragma unroll
        for (int j = 0; j < 4; ++j) {
            #pragma unroll
            for (int nt = 0; nt < 8; ++nt) {
                const float res = WS ? bf2f(rp[j * 4096 + nt * 16]) : fp[j * 4096 + nt * 16];
                const float v = gelu_fast(acc[nt][j] + b1[nt]) + res;
                s[j] += v; s2[j] += v * v;
            }
        }
        float mu[4], rs[4];
        #pragma unroll
        for (int j = 0; j < 4; ++j) {
            #pragma unroll
            for (int m = 8; m >= 1; m >>= 1) {
                s[j]  += __shfl_xor(s[j],  m, 64);
                s2[j] += __shfl_xor(s2[j], m, 64);
            }
            mu[j] = s[j] * (1.0f / 128.0f);
            const float var = fmaxf(s2[j] * (1.0f / 128.0f) - mu[j] * mu[j], 0.f);
            rs[j] = rsqrtf(var + LN_EPS);
        }
        float* op = out + r0;
        #pragma unroll
        for (int j = 0; j < 4; ++j) {
            #pragma unroll
            for (int nt = 0; nt < 8; ++nt) {
                const float res = WS ? bf2f(rp[j * 4096 + nt * 16]) : fp[j * 4096 + nt * 16];
                const float v = gelu_fast(acc[nt][j] + b1[nt]) + res;
                op[j * 4096 + nt * 16] = (v - mu[j]) * rs[j] * gm[nt] + bt[nt];
            }
        }
    };
    epilogue(acc0, 0);
    epilogue(acc1, 1);
}

extern "C" void kernel_launch(void* const* d_in, const int* in_sizes, int n_in,
                              void* d_out, int out_size, void* d_ws, size_t ws_size,
                              hipStream_t stream) {
    const float* x     = (const float*)d_in[0];
    const int*   idx   = (const int*)d_in[1];
    const float* W     = (const float*)d_in[2];
    const float* b     = (const float*)d_in[3];
    const float* gamma = (const float*)d_in[4];
    const float* beta  = (const float*)d_in[5];
    float* out = (float*)d_out;
    short* Wf  = (short*)d_ws;                       // 2 MB bf16 fragment-layout W

    const int B = in_sizes[0] / E_DIM;               // 16384
    const size_t wfElems  = (size_t)G_DIM * 2 * D_DIM * D_DIM;       // 1 Mi shorts
    const size_t actElems = (size_t)B * G_DIM * D_DIM;               // 64 Mi shorts
    const bool useWs = ws_size >= (wfElems + actElems) * sizeof(short);
    short* actH = Wf + wfElems;

    ssb_wprep_kernel<<<dim3(512), 256, 0, stream>>>(W, Wf);
    if (useWs) {
        ssb_gather_kernel<true ><<<dim3(B / ROWS1), 256, 0, stream>>>(x, idx, out, actH);
        ssb_mfma_kernel <true ><<<dim3(B / BM, G_DIM), 256, 0, stream>>>(Wf, actH, b, gamma, beta, out);
    } else {
        ssb_gather_kernel<false><<<dim3(B / ROWS1), 256, 0, stream>>>(x, idx, out, actH);
        ssb_mfma_kernel <false><<<dim3(B / BM, G_DIM), 256, 0, stream>>>(Wf, actH, b, gamma, beta, out);
    }
}